// Round 1
// baseline (85.035 us; speedup 1.0000x reference)
//
#include <hip/hip_runtime.h>

#define D        128
#define K2       256
#define M_TILE   32
#define THREADS  512
#define B_ROWS   131072
#define NTILES   (B_ROWS / M_TILE)   // 4096
#define GRID_BLOCKS 512
#define LDA      264                 // bf16 elems per LDS row (256 + 8 pad -> 528B stride)
#define LDS_ST   132                 // f32 elems per state row  (528B stride)

typedef __bf16  bf16x8  __attribute__((ext_vector_type(8)));
typedef float   f32x4   __attribute__((ext_vector_type(4)));
typedef unsigned short ushort8 __attribute__((ext_vector_type(8)));

__device__ __forceinline__ unsigned short f2bf(float f) {
    // round-to-nearest-even f32 -> bf16 bits
    unsigned int u = __float_as_uint(f);
    u += 0x7fffu + ((u >> 16) & 1u);
    return (unsigned short)(u >> 16);
}

__device__ __forceinline__ bf16x8 us2bf(ushort8 u) {
    union { ushort8 u; bf16x8 b; } c; c.u = u; return c.b;
}

__device__ __forceinline__ float fast_tanh(float x) {
    x = fminf(15.f, fmaxf(-15.f, x));
    float e = __expf(2.f * x);
    return (e - 1.f) / (e + 1.f);
}
__device__ __forceinline__ float fast_sigmoid(float x) {
    return 1.f / (1.f + __expf(-x));
}

__global__ __launch_bounds__(THREADS, 4)
void liquid_cell(const float* __restrict__ x,      const float* __restrict__ st,
                 const float* __restrict__ w_in,   const float* __restrict__ b_in,
                 const float* __restrict__ w_rec,  const float* __restrict__ w_gate,
                 const float* __restrict__ b_gate, const float* __restrict__ bias,
                 const float* __restrict__ log_step,
                 const float* __restrict__ gamma,  const float* __restrict__ beta,
                 float* __restrict__ out)
{
    __shared__ __align__(16) unsigned short A1[M_TILE * LDA];  // [x | tanh(state)] bf16
    __shared__ __align__(16) unsigned short A2[M_TILE * LDA];  // LN([x|state])    bf16
    __shared__ __align__(16) float SBUF[M_TILE * LDS_ST];      // state f32 for epilogue
    __shared__ float stepL[D], biasdL[D], bgateL[D];
    __shared__ float gammaL[K2], betaL[K2];

    const int tid  = threadIdx.x;
    const int lane = tid & 63;
    const int wave = tid >> 6;            // 0..7, owns output cols [wave*16, wave*16+16)

    // ---- one-time parameter staging ----
    if (tid < D) {
        stepL[tid]  = fast_sigmoid(log_step[tid]);
        biasdL[tid] = b_in[tid] + bias[tid];
        bgateL[tid] = b_gate[tid];
    }
    if (tid < K2) { gammaL[tid] = gamma[tid]; betaL[tid] = beta[tid]; }

    // ---- persistent weight B-fragments in registers ----
    // B-frag layout for mfma_f32_16x16x32_bf16: lane holds B[k][n], n = lane&15,
    // k = kb*32 + (lane>>4)*8 + j  (8 contiguous k)
    const int hcol = wave * 16 + (lane & 15);
    const int koff = (lane >> 4) * 8;
    bf16x8 wd[8], wg[8];
    #pragma unroll
    for (int kb = 0; kb < 8; ++kb) {
        const int k = kb * 32 + koff;
        const float* src1 = (k < 128) ? (w_in  + hcol * 128 + k)
                                      : (w_rec + hcol * 128 + (k - 128));
        const float* src2 = w_gate + hcol * 256 + k;
        ushort8 u1, u2;
        #pragma unroll
        for (int j = 0; j < 8; ++j) { u1[j] = f2bf(src1[j]); u2[j] = f2bf(src2[j]); }
        wd[kb] = us2bf(u1);
        wg[kb] = us2bf(u2);
    }
    __syncthreads();

    const int r  = tid >> 4;              // row within tile, 0..31
    const int c0 = (tid & 15) * 8;        // 8-col chunk, 0..120

    for (int tile = blockIdx.x; tile < NTILES; tile += gridDim.x) {
        const long grow = (long)tile * M_TILE + r;

        // ---- phase A: load + preprocess (regs only, overlaps prior tile's sync) ----
        float xv[8], sv[8];
        const float* xp = x  + grow * D + c0;
        const float* sp = st + grow * D + c0;
        *(f32x4*)(xv)     = *(const f32x4*)(xp);
        *(f32x4*)(xv + 4) = *(const f32x4*)(xp + 4);
        *(f32x4*)(sv)     = *(const f32x4*)(sp);
        *(f32x4*)(sv + 4) = *(const f32x4*)(sp + 4);

        float sum = 0.f, sq = 0.f;
        #pragma unroll
        for (int j = 0; j < 8; ++j) {
            sum += xv[j] + sv[j];
            sq  += xv[j] * xv[j] + sv[j] * sv[j];
        }
        #pragma unroll
        for (int m = 1; m < 16; m <<= 1) {
            sum += __shfl_xor(sum, m);
            sq  += __shfl_xor(sq,  m);
        }
        const float mu   = sum * (1.f / 256.f);
        const float var  = sq * (1.f / 256.f) - mu * mu;
        const float rstd = rsqrtf(var + 1e-5f);

        ushort8 a1x, a1s, a2x, a2s;
        #pragma unroll
        for (int j = 0; j < 8; ++j) {
            a1x[j] = f2bf(xv[j]);
            a1s[j] = f2bf(fast_tanh(sv[j]));
            a2x[j] = f2bf((xv[j] - mu) * rstd * gammaL[c0 + j]       + betaL[c0 + j]);
            a2s[j] = f2bf((sv[j] - mu) * rstd * gammaL[128 + c0 + j] + betaL[128 + c0 + j]);
        }

        __syncthreads();   // prior tile's LDS reads are done
        *(ushort8*)(A1 + r * LDA + c0)       = a1x;
        *(ushort8*)(A1 + r * LDA + 128 + c0) = a1s;
        *(ushort8*)(A2 + r * LDA + c0)       = a2x;
        *(ushort8*)(A2 + r * LDA + 128 + c0) = a2s;
        *(f32x4*)(SBUF + r * LDS_ST + c0)     = *(const f32x4*)(sv);
        *(f32x4*)(SBUF + r * LDS_ST + c0 + 4) = *(const f32x4*)(sv + 4);
        __syncthreads();

        // ---- phase B: MFMA ----
        f32x4 acc1[2], acc2[2];
        #pragma unroll
        for (int ms = 0; ms < 2; ++ms) { acc1[ms] = (f32x4)(0.f); acc2[ms] = (f32x4)(0.f); }

        const int arow = lane & 15;
        #pragma unroll
        for (int ms = 0; ms < 2; ++ms) {
            const unsigned short* pa1 = A1 + (ms * 16 + arow) * LDA + koff;
            const unsigned short* pa2 = A2 + (ms * 16 + arow) * LDA + koff;
            #pragma unroll
            for (int kb = 0; kb < 8; ++kb) {
                bf16x8 a = us2bf(*(const ushort8*)(pa1 + kb * 32));
                acc1[ms] = __builtin_amdgcn_mfma_f32_16x16x32_bf16(a, wd[kb], acc1[ms], 0, 0, 0);
            }
            #pragma unroll
            for (int kb = 0; kb < 8; ++kb) {
                bf16x8 a = us2bf(*(const ushort8*)(pa2 + kb * 32));
                acc2[ms] = __builtin_amdgcn_mfma_f32_16x16x32_bf16(a, wg[kb], acc2[ms], 0, 0, 0);
            }
        }

        // ---- epilogue: activation + blend + store ----
        const int   ocol  = wave * 16 + (lane & 15);
        const float stepv = stepL[ocol];
        const float bd    = biasdL[ocol];
        const float bg    = bgateL[ocol];
        #pragma unroll
        for (int ms = 0; ms < 2; ++ms) {
            #pragma unroll
            for (int rg = 0; rg < 4; ++rg) {
                const int row    = ms * 16 + (lane >> 4) * 4 + rg;
                const float drive = acc1[ms][rg] + bd;
                const float g     = acc2[ms][rg] + bg;
                const float target = fast_tanh(drive);
                const float gate   = fast_sigmoid(g);
                const float blend  = fminf(stepv * gate, 1.f);
                const float s      = SBUF[row * LDS_ST + ocol];
                out[((long)tile * M_TILE + row) * D + ocol] = s + blend * (target - s);
            }
        }
    }
}

extern "C" void kernel_launch(void* const* d_in, const int* in_sizes, int n_in,
                              void* d_out, int out_size, void* d_ws, size_t ws_size,
                              hipStream_t stream) {
    const float* x        = (const float*)d_in[0];
    const float* st       = (const float*)d_in[1];
    const float* w_in     = (const float*)d_in[2];
    const float* b_in     = (const float*)d_in[3];
    const float* w_rec    = (const float*)d_in[4];
    const float* w_gate   = (const float*)d_in[5];
    const float* b_gate   = (const float*)d_in[6];
    const float* bias     = (const float*)d_in[7];
    const float* log_step = (const float*)d_in[8];
    const float* gamma    = (const float*)d_in[9];
    const float* beta     = (const float*)d_in[10];
    float* out = (float*)d_out;

    hipLaunchKernelGGL(liquid_cell, dim3(GRID_BLOCKS), dim3(THREADS), 0, stream,
                       x, st, w_in, b_in, w_rec, w_gate, b_gate, bias,
                       log_step, gamma, beta, out);
}